// Round 4
// baseline (136.677 us; speedup 1.0000x reference)
//
#include <hip/hip_runtime.h>
#include <stdint.h>

#define NTOT 8192
#define BHALF 4096
#define DZ 512
#define DC 128
#define TEMPV 0.5f
#define FIXM 16.0f
#define LOG2E 1.44269504f
#define FM2 23.08312065f   // FIXM * LOG2E
#define SCALE1 0x7F7F7F7F  // e8m0 unit scales

typedef __attribute__((ext_vector_type(4))) float f32x4;
typedef __attribute__((ext_vector_type(4))) float floatx4;
typedef __attribute__((ext_vector_type(2))) float float2v;
typedef __attribute__((ext_vector_type(2))) unsigned long ulong2v;  // 16B chunk
typedef __attribute__((ext_vector_type(8))) int int8v;              // 32B MFMA operand
typedef __attribute__((ext_vector_type(4))) unsigned int uint4v;

// MX-scaled fp8 MFMA, K=128, unit scales. cbsz=0/blgp=0 -> FP8 e4m3 A and B.
#define MFMAS(a, b, c) \
  __builtin_amdgcn_mfma_scale_f32_16x16x128_f8f6f4((a), (b), (c), 0, 0, 0, SCALE1, 0, SCALE1)

__device__ __forceinline__ uint32_t pk4_e4m3(float f0, float f1, float f2, float f3) {
  int w = 0;
  w = __builtin_amdgcn_cvt_pk_fp8_f32(f0, f1, w, false);
  w = __builtin_amdgcn_cvt_pk_fp8_f32(f2, f3, w, true);
  return (uint32_t)w;
}

__device__ __forceinline__ int8v mk8(ulong2v lo, ulong2v hi) {
  int8v r;
  ((ulong2v*)&r)[0] = lo;
  ((ulong2v*)&r)[1] = hi;
  return r;
}

// ---------------- convert: fp32 -> fp8 e4m3 (frag-pair-tiled) + exact pos dots ----------------
// (unchanged from verified R13/R16 version)
__global__ void convert_kernel(const float* __restrict__ z_i, const float* __restrict__ z_j,
                               const float* __restrict__ c_i, const float* __restrict__ c_j,
                               uint8_t* __restrict__ zbT, uint8_t* __restrict__ cbT,
                               float* __restrict__ pos2, float* __restrict__ out) {
  const int ZC = NTOT * DZ / 16;   // 262144 chunks
  const int CC = NTOT * DC / 16;   // 65536  (ZC+CC = 1280*256 exactly)

  if (blockIdx.x >= 1280) {
    if (blockIdx.x == 1280 && threadIdx.x == 0) out[0] = 0.0f;
    const int wv   = (blockIdx.x - 1280) * 4 + (threadIdx.x >> 6);  // 0..1023
    const int lane = threadIdx.x & 63;
#pragma unroll
    for (int q = 0; q < 4; ++q) {
      const int p = wv * 4 + q;
      const float* a = z_i + (size_t)p * DZ + lane * 8;
      const float* b = z_j + (size_t)p * DZ + lane * 8;
      floatx4 a0 = *(const floatx4*)a, a1 = *(const floatx4*)(a + 4);
      floatx4 b0 = *(const floatx4*)b, b1 = *(const floatx4*)(b + 4);
      float d = a0[0]*b0[0] + a0[1]*b0[1] + a0[2]*b0[2] + a0[3]*b0[3]
              + a1[0]*b1[0] + a1[1]*b1[1] + a1[2]*b1[2] + a1[3]*b1[3];
#pragma unroll
      for (int off = 1; off < 64; off <<= 1) d += __shfl_xor(d, off);
      if (lane == 0) pos2[p] = 2.0f * d;
    }
    return;
  }

  int i = blockIdx.x * blockDim.x + threadIdx.x;
  const float* src;
  uint8_t* dst;
  int k0;
  if (i < ZC) {
    int lane = i & 63, g = i >> 6;
    int ct = g >> 3, cc = g & 7;
    int ln = lane & 15, lq = lane >> 4;
    int row = ct * 16 + ln;
    k0 = cc * 64 + lq * 8;
    src = (row < BHALF) ? (z_i + (size_t)row * DZ) : (z_j + (size_t)(row - BHALF) * DZ);
    dst = zbT + (size_t)i * 16;
  } else {
    int i2 = i - ZC;
    int lane = i2 & 63, g = i2 >> 6;
    int ct = g >> 1, cc = g & 1;
    int ln = lane & 15, lq = lane >> 4;
    int row = ct * 16 + ln;
    k0 = cc * 64 + lq * 8;
    src = (row < BHALF) ? (c_i + (size_t)row * DC) : (c_j + (size_t)(row - BHALF) * DC);
    dst = cbT + (size_t)i2 * 16;
  }
  floatx4 a0 = *(const floatx4*)(src + k0);
  floatx4 a1 = *(const floatx4*)(src + k0 + 4);
  floatx4 b0 = *(const floatx4*)(src + k0 + 32);
  floatx4 b1 = *(const floatx4*)(src + k0 + 36);
  uint4v o;
  o.x = pk4_e4m3(a0[0], a0[1], a0[2], a0[3]);
  o.y = pk4_e4m3(a1[0], a1[1], a1[2], a1[3]);
  o.z = pk4_e4m3(b0[0], b0[1], b0[2], b0[3]);
  o.w = pk4_e4m3(b1[0], b1[1], b1[2], b1[3]);
  *(uint4v*)dst = o;
}

// ---------------- fused symmetric flash-lse: upper-triangle 128x128 blocks ----------------
// R20 traffic-halving restructure. R17/R18/R19 (three different schedules) all pinned at
// ~44 us -> invariant = B-operand bytes/wave: 32-row waves re-read 666 MB of B panels
// (L2 floor ~19 us @100%, ~30 us realistic) on top of MFMA 9.3 us + VALU ~15 us with
// mediocre overlap. Fix: 64 rows/wave (4 row-tiles of A resident, ~160 VGPR) -> B traffic
// halves to 333 MB (~10 us floor), per-output address/loop VALU halves too. One wave per
// (visit, half-band): 4160 blocks x 64 thr, no LDS, no barriers (5 MB dataset is
// L2-resident; lesson #7). unroll 1 + all-B-loads-first keeps peak live regs ~250
// under the (64,2) 256-VGPR cap. XCD-chunk swizzle (4160 = 8*520, bijective).
__launch_bounds__(64, 2)
__global__ void fused_kernel(const uint8_t* __restrict__ zbT, const uint8_t* __restrict__ cbT,
                             float* __restrict__ RP, float* __restrict__ CPW) {
  const int bx  = blockIdx.x;
  const int swz = (bx & 7) * 520 + (bx >> 3);
  const int t   = swz >> 1;       // visit 0..2079
  const int w   = swz & 1;        // half-band 0..1 (64 rows each)

  // band-major triangular decode: t -> (rb, cb), rb <= cb
  const int u = 2079 - t;
  int k = (int)((__builtin_sqrtf(8.0f * (float)u + 1.0f) - 1.0f) * 0.5f);
  while ((k + 1) * (k + 2) / 2 <= u) ++k;
  while (k * (k + 1) / 2 > u) --k;
  const int rb = 63 - k;
  const int cb = 63 - (u - k * (k + 1) / 2);
  const bool diagBlk = (rb == cb);
  const bool pairBlk = (cb == rb + 32);

  const int lane = threadIdx.x;   // 64-thread block = 1 wave
  const int lq   = lane >> 4;
  const int ln   = lane & 15;
  const int row_w = rb * 128 + w * 64;

  // A operands for this wave's 4 row-tiles (resident): z 128 VGPR + c 32 VGPR
  int8v a_z[4][4], a_c[4];
#pragma unroll
  for (int rt_i = 0; rt_i < 4; ++rt_i) {
    const int rt = rb * 8 + 4 * w + rt_i;
    const uint8_t* p = zbT + ((size_t)rt * 512 + lane) * 16;
#pragma unroll
    for (int kq = 0; kq < 4; ++kq)
      a_z[rt_i][kq] = mk8(*(const ulong2v*)(p + (size_t)(2 * kq) * 1024),
                          *(const ulong2v*)(p + (size_t)(2 * kq + 1) * 1024));
    const uint8_t* qc = cbT + ((size_t)rt * 128 + lane) * 16;
    a_c[rt_i] = mk8(*(const ulong2v*)qc, *(const ulong2v*)(qc + 1024));
  }

  float l_[4][4] = {{0.f,0.f,0.f,0.f},{0.f,0.f,0.f,0.f},{0.f,0.f,0.f,0.f},{0.f,0.f,0.f,0.f}};

#pragma unroll 1
  for (int it8 = 0; it8 < 8; ++it8) {
    const int ct = cb * 8 + it8;
    float lcv = 0.0f;

    // wave-uniform skip: diag blocks, col-tiles fully below this wave's 64 rows
    if (!(diagBlk && it8 < 4 * w)) {
      const uint8_t* pz = zbT + ((size_t)ct * 512 + lane) * 16;
      const uint8_t* pc = cbT + ((size_t)ct * 128 + lane) * 16;

      // issue ALL B loads up front (10 x 16B): latency covered by the c-MFMA chain
      const int8v bc = mk8(*(const ulong2v*)pc, *(const ulong2v*)(pc + 1024));
      int8v bz[4];
#pragma unroll
      for (int kq = 0; kq < 4; ++kq)
        bz[kq] = mk8(*(const ulong2v*)(pz + (size_t)(2 * kq) * 1024),
                     *(const ulong2v*)(pz + (size_t)(2 * kq + 1) * 1024));

      __builtin_amdgcn_s_setprio(1);
      f32x4 ac[4];
#pragma unroll
      for (int rt_i = 0; rt_i < 4; ++rt_i) {
        f32x4 zz = {0.f, 0.f, 0.f, 0.f};
        ac[rt_i] = MFMAS(a_c[rt_i], bc, zz);
      }
      // tv = 1/max(c.c, 0.5) — VALU overlaps the z-MFMA issue below
      f32x4 tv[4];
#pragma unroll
      for (int rt_i = 0; rt_i < 4; ++rt_i)
#pragma unroll
        for (int r = 0; r < 4; ++r)
          tv[rt_i][r] = __builtin_amdgcn_rcpf(fmaxf(ac[rt_i][r], TEMPV));

      f32x4 az[4] = {{0.f,0.f,0.f,0.f},{0.f,0.f,0.f,0.f},{0.f,0.f,0.f,0.f},{0.f,0.f,0.f,0.f}};
#pragma unroll
      for (int kq = 0; kq < 4; ++kq) {
#pragma unroll
        for (int rt_i = 0; rt_i < 4; ++rt_i)
          az[rt_i] = MFMAS(a_z[rt_i][kq], bz[kq], az[rt_i]);
      }
      __builtin_amdgcn_s_setprio(0);

      const int gc = cb * 128 + it8 * 16 + ln;
#pragma unroll
      for (int rt_i = 0; rt_i < 4; ++rt_i) {
        const int grb = row_w + rt_i * 16 + lq * 4;
        const bool pairTile = pairBlk && (it8 == 4 * w + rt_i);
#pragma unroll
        for (int r = 0; r < 4; ++r) {
          float sv = az[rt_i][r] * tv[rt_i][r];
          float e  = __builtin_amdgcn_exp2f(__builtin_fmaf(sv, LOG2E, -FM2));
          if (diagBlk && gc <= grb + r) e = 0.0f;        // diag + lower half
          if (pairTile && ln == lq * 4 + r) e = 0.0f;    // pair exclusion
          l_[rt_i][r] += e;
          lcv += e;
        }
      }
    }

    // col partial for this tile over this wave's 64 rows -> private slot (no sync needed)
    float v = lcv;
    v += __shfl_xor(v, 16);
    v += __shfl_xor(v, 32);
    if (lq == 0)
      CPW[((size_t)(cb * 128 + it8 * 16 + ln)) * 128 + (size_t)rb * 2 + w] = v;
  }

  // row partials -> RP[row][cb] (xor offs 1..8 stay within the 16-lane ln group)
#pragma unroll
  for (int rt_i = 0; rt_i < 4; ++rt_i)
#pragma unroll
    for (int r = 0; r < 4; ++r) {
      float ll = l_[rt_i][r];
#pragma unroll
      for (int off = 1; off < 16; off <<= 1) ll += __shfl_xor(ll, off);
      if (ln == 0) RP[(size_t)(row_w + rt_i * 16 + lq * 4 + r) * 64 + cb] = ll;
    }
}

// ---------------- finalize: triangular partial merge + pos + reduction ----------------
// Row r (R=r>>7): negsum = sum_{cb>=R} RP[r][cb] + sum_{rb<=R, w} CPW[r][rb*2+w].
// CPW read as float2/lane (lane l covers rb=l, 2 w-slots) -> 512B coalesced per wave.
__global__ void finalize_kernel(const float* __restrict__ RP, const float* __restrict__ CPW,
                                const float* __restrict__ pos2, float* __restrict__ out) {
  const int tid  = threadIdx.x;
  const int w    = tid >> 6;
  const int lane = tid & 63;
  const int row  = blockIdx.x * 16 + w;
  const int R    = row >> 7;

  float v = 0.0f;
  if (lane >= R) v += RP[(size_t)row * 64 + lane];
  {
    const float2v c2 = *(const float2v*)(CPW + (size_t)row * 128 + lane * 2);
    if (lane <= R) v += c2[0] + c2[1];
  }
#pragma unroll
  for (int off = 1; off < 64; off <<= 1) v += __shfl_xor(v, off);

  __shared__ float red[16];
  if (lane == 0) {
    float pos  = pos2[row & (BHALF - 1)];
    float lneg = FIXM + __logf(v);
    float hi = fmaxf(lneg, pos), lo = fminf(lneg, pos);
    float lse = hi + __logf(1.0f + __expf(lo - hi));
    red[w] = lse - pos;
  }
  __syncthreads();
  if (tid == 0) {
    float s = 0.0f;
#pragma unroll
    for (int i = 0; i < 16; ++i) s += red[i];
    atomicAdd(out, s * (1.0f / NTOT));
  }
}

extern "C" void kernel_launch(void* const* d_in, const int* in_sizes, int n_in,
                              void* d_out, int out_size, void* d_ws, size_t ws_size,
                              hipStream_t stream) {
  const float* z_i = (const float*)d_in[0];
  const float* z_j = (const float*)d_in[1];
  const float* c_i = (const float*)d_in[2];
  const float* c_j = (const float*)d_in[3];

  uint8_t* zbT = (uint8_t*)d_ws;                        // 4 MB fp8 z (tiled)
  uint8_t* cbT = zbT + (size_t)NTOT * DZ;               // 1 MB fp8 c (tiled)
  float* RP   = (float*)(cbT + (size_t)NTOT * DC);      // 2 MB
  float* CPW  = RP + (size_t)NTOT * 64;                 // 4 MB (per-wave col slots)
  float* pos2 = CPW + (size_t)NTOT * 128;               // 16 KB

  convert_kernel<<<1536, 256, 0, stream>>>(z_i, z_j, c_i, c_j, zbT, cbT, pos2, (float*)d_out);
  fused_kernel<<<4160, 64, 0, stream>>>(zbT, cbT, RP, CPW);
  finalize_kernel<<<512, 1024, 0, stream>>>(RP, CPW, pos2, (float*)d_out);
}

// Round 5
// 119.200 us; speedup vs baseline: 1.1466x; 1.1466x over previous
//
#include <hip/hip_runtime.h>
#include <stdint.h>

#define NTOT 8192
#define BHALF 4096
#define DZ 512
#define DC 128
#define TEMPV 0.5f
#define FIXM 16.0f
#define LOG2E 1.44269504f
#define FM2 23.08312065f   // FIXM * LOG2E
#define SCALE1 0x7F7F7F7F  // e8m0 unit scales

typedef __attribute__((ext_vector_type(4))) float f32x4;
typedef __attribute__((ext_vector_type(4))) float floatx4;
typedef __attribute__((ext_vector_type(2))) unsigned long ulong2v;  // 16B chunk
typedef __attribute__((ext_vector_type(8))) int int8v;              // 32B MFMA operand
typedef __attribute__((ext_vector_type(4))) unsigned int uint4v;

// MX-scaled fp8 MFMA, K=128, unit scales. cbsz=0/blgp=0 -> FP8 e4m3 A and B.
#define MFMAS(a, b, c) \
  __builtin_amdgcn_mfma_scale_f32_16x16x128_f8f6f4((a), (b), (c), 0, 0, 0, SCALE1, 0, SCALE1)

__device__ __forceinline__ uint32_t pk4_e4m3(float f0, float f1, float f2, float f3) {
  int w = 0;
  w = __builtin_amdgcn_cvt_pk_fp8_f32(f0, f1, w, false);
  w = __builtin_amdgcn_cvt_pk_fp8_f32(f2, f3, w, true);
  return (uint32_t)w;
}

__device__ __forceinline__ int8v mk8(ulong2v lo, ulong2v hi) {
  int8v r;
  ((ulong2v*)&r)[0] = lo;
  ((ulong2v*)&r)[1] = hi;
  return r;
}

// ---------------- convert: fp32 -> fp8 e4m3 (frag-pair-tiled) + fused pos dots ----------------
// R21 single-pass restructure: one wave per pair-row p. Lanes 0-31 hold z_i[p], lanes
// 32-63 hold z_j[p] (same k-coverage per lane pair); each lane packs its 16 elems into
// the IDENTICAL zbT tiled chunk as the old layout, and the exact fp32 pair dot comes
// from shfl_xor(.,32) cross-half products — z read ONCE (33.6 MB, was 50.4), separate
// pos pass eliminated. c-section (blocks 1024..1279) unchanged from verified mapping.
__global__ void convert_kernel(const float* __restrict__ z_i, const float* __restrict__ z_j,
                               const float* __restrict__ c_i, const float* __restrict__ c_j,
                               uint8_t* __restrict__ zbT, uint8_t* __restrict__ cbT,
                               float* __restrict__ pos2, float* __restrict__ out) {
  if (blockIdx.x < 1024) {
    // z-section: 4 waves/block, wave = one pair-row p (4096 pairs total)
    const int p    = blockIdx.x * 4 + (threadIdx.x >> 6);   // 0..4095
    const int lane = threadIdx.x & 63;
    const int half = lane >> 5;          // 0: z_i row p, 1: z_j row p (global row p+4096)
    const int l    = lane & 31;
    const int cc   = l >> 2;
    const int lq   = l & 3;
    const int k0   = cc * 64 + lq * 8;

    const float* src = half ? (z_j + (size_t)p * DZ) : (z_i + (size_t)p * DZ);
    floatx4 a0 = *(const floatx4*)(src + k0);
    floatx4 a1 = *(const floatx4*)(src + k0 + 4);
    floatx4 b0 = *(const floatx4*)(src + k0 + 32);
    floatx4 b1 = *(const floatx4*)(src + k0 + 36);

    // pack fp8 chunk -> same tiled position as the verified layout
    uint4v o;
    o.x = pk4_e4m3(a0[0], a0[1], a0[2], a0[3]);
    o.y = pk4_e4m3(a1[0], a1[1], a1[2], a1[3]);
    o.z = pk4_e4m3(b0[0], b0[1], b0[2], b0[3]);
    o.w = pk4_e4m3(b1[0], b1[1], b1[2], b1[3]);
    const int row = half ? (p + BHALF) : p;
    const size_t ci = (((size_t)(row >> 4) * 8 + cc) * 64 + (size_t)lq * 16 + (row & 15));
    *(uint4v*)(zbT + ci * 16) = o;

    // exact fp32 pair dot: cross-half products via shfl_xor 32, then 5-level reduce
    float d = 0.0f;
#pragma unroll
    for (int m = 0; m < 4; ++m) d = __builtin_fmaf(a0[m], __shfl_xor(a0[m], 32), d);
#pragma unroll
    for (int m = 0; m < 4; ++m) d = __builtin_fmaf(a1[m], __shfl_xor(a1[m], 32), d);
#pragma unroll
    for (int m = 0; m < 4; ++m) d = __builtin_fmaf(b0[m], __shfl_xor(b0[m], 32), d);
#pragma unroll
    for (int m = 0; m < 4; ++m) d = __builtin_fmaf(b1[m], __shfl_xor(b1[m], 32), d);
#pragma unroll
    for (int off = 1; off < 32; off <<= 1) d += __shfl_xor(d, off);
    if (lane == 0) pos2[p] = 2.0f * d;
    return;
  }

  // c-section: blocks 1024..1279, verified chunk mapping (i2 in [0, 65536))
  if (blockIdx.x == 1024 && threadIdx.x == 0) out[0] = 0.0f;
  const int i2   = (blockIdx.x - 1024) * 256 + threadIdx.x;
  const int lane = i2 & 63, g = i2 >> 6;
  const int ct = g >> 1, cc = g & 1;
  const int ln = lane & 15, lq = lane >> 4;
  const int row = ct * 16 + ln;
  const int k0 = cc * 64 + lq * 8;
  const float* src = (row < BHALF) ? (c_i + (size_t)row * DC) : (c_j + (size_t)(row - BHALF) * DC);
  uint8_t* dst = cbT + (size_t)i2 * 16;

  floatx4 a0 = *(const floatx4*)(src + k0);
  floatx4 a1 = *(const floatx4*)(src + k0 + 4);
  floatx4 b0 = *(const floatx4*)(src + k0 + 32);
  floatx4 b1 = *(const floatx4*)(src + k0 + 36);
  uint4v o;
  o.x = pk4_e4m3(a0[0], a0[1], a0[2], a0[3]);
  o.y = pk4_e4m3(a1[0], a1[1], a1[2], a1[3]);
  o.z = pk4_e4m3(b0[0], b0[1], b0[2], b0[3]);
  o.w = pk4_e4m3(b1[0], b1[1], b1[2], b1[3]);
  *(uint4v*)dst = o;
}

// ---------------- fused symmetric flash-lse: upper-triangle 128x128 blocks ----------------
// R19 structure (verified ~44 us): no LDS, no barriers (5 MB fp8 dataset is L2-resident),
// one independent wave per (visit, band-quarter), B operands straight from L2,
// per-wave col slots CPW (no atomics). R20's 64-row variant SPILLED (VGPR capped 128)
// and regressed 44->62 us — do not widen A-residency without checking VGPR_Count.
__launch_bounds__(64, 3)
__global__ void fused_kernel(const uint8_t* __restrict__ zbT, const uint8_t* __restrict__ cbT,
                             float* __restrict__ RP, float* __restrict__ CPW) {
  // 8320 = 8 * 1040 exactly -> bijective XCD-chunk swizzle
  const int bx  = blockIdx.x;
  const int swz = (bx & 7) * 1040 + (bx >> 3);
  const int t   = swz >> 2;       // visit 0..2079
  const int w   = swz & 3;        // band-quarter 0..3

  // band-major triangular decode: t -> (rb, cb), rb <= cb
  const int u = 2079 - t;
  int k = (int)((__builtin_sqrtf(8.0f * (float)u + 1.0f) - 1.0f) * 0.5f);
  while ((k + 1) * (k + 2) / 2 <= u) ++k;
  while (k * (k + 1) / 2 > u) --k;
  const int rb = 63 - k;
  const int cb = 63 - (u - k * (k + 1) / 2);
  const bool diagBlk = (rb == cb);
  const bool pairBlk = (cb == rb + 32);

  const int lane = threadIdx.x;   // 64-thread block = 1 wave
  const int lq   = lane >> 4;
  const int ln   = lane & 15;
  const int row_w = rb * 128 + w * 32;

  // A operands for this wave's 2 row-tiles (resident): z 64 VGPR + c 16 VGPR
  int8v a_z[2][4], a_c[2];
#pragma unroll
  for (int rt_i = 0; rt_i < 2; ++rt_i) {
    const int rt = rb * 8 + 2 * w + rt_i;
    const uint8_t* p = zbT + ((size_t)rt * 512 + lane) * 16;
#pragma unroll
    for (int kq = 0; kq < 4; ++kq)
      a_z[rt_i][kq] = mk8(*(const ulong2v*)(p + (size_t)(2 * kq) * 1024),
                          *(const ulong2v*)(p + (size_t)(2 * kq + 1) * 1024));
    const uint8_t* qc = cbT + ((size_t)rt * 128 + lane) * 16;
    a_c[rt_i] = mk8(*(const ulong2v*)qc, *(const ulong2v*)(qc + 1024));
  }

  float l_[2][4] = {{0.f, 0.f, 0.f, 0.f}, {0.f, 0.f, 0.f, 0.f}};

#pragma unroll
  for (int it8 = 0; it8 < 8; ++it8) {
    const int ct = cb * 8 + it8;
    float lcv = 0.0f;

    // wave-uniform skip: diag blocks, col-tiles fully below this wave's 32 rows
    if (!(diagBlk && it8 < 2 * w)) {
      const uint8_t* pz = zbT + ((size_t)ct * 512 + lane) * 16;
      const uint8_t* pc = cbT + ((size_t)ct * 128 + lane) * 16;

      // B operands straight from L2 (identical bytes the LDS stager used to move)
      const int8v bc = mk8(*(const ulong2v*)pc, *(const ulong2v*)(pc + 1024));
      int8v bz[4];
#pragma unroll
      for (int kq = 0; kq < 4; ++kq)
        bz[kq] = mk8(*(const ulong2v*)(pz + (size_t)(2 * kq) * 1024),
                     *(const ulong2v*)(pz + (size_t)(2 * kq + 1) * 1024));

      f32x4 ac[2] = {{0.f, 0.f, 0.f, 0.f}, {0.f, 0.f, 0.f, 0.f}};
      f32x4 az[2] = {{0.f, 0.f, 0.f, 0.f}, {0.f, 0.f, 0.f, 0.f}};

      __builtin_amdgcn_s_setprio(1);
      ac[0] = MFMAS(a_c[0], bc, ac[0]);
      ac[1] = MFMAS(a_c[1], bc, ac[1]);
#pragma unroll
      for (int kq = 0; kq < 4; ++kq) {
        az[0] = MFMAS(a_z[0][kq], bz[kq], az[0]);
        az[1] = MFMAS(a_z[1][kq], bz[kq], az[1]);
      }
      __builtin_amdgcn_s_setprio(0);

      const int gc = cb * 128 + it8 * 16 + ln;
#pragma unroll
      for (int rt_i = 0; rt_i < 2; ++rt_i) {
        const int grb = row_w + rt_i * 16 + lq * 4;
        const bool pairTile = pairBlk && (it8 == 2 * w + rt_i);
#pragma unroll
        for (int r = 0; r < 4; ++r) {
          float tv = fmaxf(ac[rt_i][r], TEMPV);
          float sv = az[rt_i][r] * __builtin_amdgcn_rcpf(tv);
          float e  = __builtin_amdgcn_exp2f(__builtin_fmaf(sv, LOG2E, -FM2));
          if (diagBlk && gc <= grb + r) e = 0.0f;        // diag + lower half
          if (pairTile && ln == lq * 4 + r) e = 0.0f;    // pair exclusion
          l_[rt_i][r] += e;
          lcv += e;
        }
      }
    }

    // col partial for this tile over this wave's 32 rows -> private slot (no sync needed)
    float v = lcv;
    v += __shfl_xor(v, 16);
    v += __shfl_xor(v, 32);
    if (lq == 0)
      CPW[((size_t)(cb * 128 + it8 * 16 + ln)) * 256 + (size_t)rb * 4 + w] = v;
  }

  // row partials -> RP[row][cb] (xor offs 1..8 stay within the 16-lane ln group)
#pragma unroll
  for (int rt_i = 0; rt_i < 2; ++rt_i)
#pragma unroll
    for (int r = 0; r < 4; ++r) {
      float ll = l_[rt_i][r];
#pragma unroll
      for (int off = 1; off < 16; off <<= 1) ll += __shfl_xor(ll, off);
      if (ln == 0) RP[(size_t)(row_w + rt_i * 16 + lq * 4 + r) * 64 + cb] = ll;
    }
}

// ---------------- finalize: triangular partial merge + pos + reduction ----------------
// Row r (R=r>>7): negsum = sum_{cb>=R} RP[r][cb] + sum_{rb<=R, w} CPW[r][rb*4+w].
// CPW read as float4/lane (lane l covers rb=l, 4 w-slots) -> 1 KB coalesced per wave.
__global__ void finalize_kernel(const float* __restrict__ RP, const float* __restrict__ CPW,
                                const float* __restrict__ pos2, float* __restrict__ out) {
  const int tid  = threadIdx.x;
  const int w    = tid >> 6;
  const int lane = tid & 63;
  const int row  = blockIdx.x * 16 + w;
  const int R    = row >> 7;

  float v = 0.0f;
  if (lane >= R) v += RP[(size_t)row * 64 + lane];
  {
    const floatx4 c4 = *(const floatx4*)(CPW + (size_t)row * 256 + lane * 4);
    if (lane <= R) v += c4[0] + c4[1] + c4[2] + c4[3];
  }
#pragma unroll
  for (int off = 1; off < 64; off <<= 1) v += __shfl_xor(v, off);

  __shared__ float red[16];
  if (lane == 0) {
    float pos  = pos2[row & (BHALF - 1)];
    float lneg = FIXM + __logf(v);
    float hi = fmaxf(lneg, pos), lo = fminf(lneg, pos);
    float lse = hi + __logf(1.0f + __expf(lo - hi));
    red[w] = lse - pos;
  }
  __syncthreads();
  if (tid == 0) {
    float s = 0.0f;
#pragma unroll
    for (int i = 0; i < 16; ++i) s += red[i];
    atomicAdd(out, s * (1.0f / NTOT));
  }
}

extern "C" void kernel_launch(void* const* d_in, const int* in_sizes, int n_in,
                              void* d_out, int out_size, void* d_ws, size_t ws_size,
                              hipStream_t stream) {
  const float* z_i = (const float*)d_in[0];
  const float* z_j = (const float*)d_in[1];
  const float* c_i = (const float*)d_in[2];
  const float* c_j = (const float*)d_in[3];

  uint8_t* zbT = (uint8_t*)d_ws;                        // 4 MB fp8 z (tiled)
  uint8_t* cbT = zbT + (size_t)NTOT * DZ;               // 1 MB fp8 c (tiled)
  float* RP   = (float*)(cbT + (size_t)NTOT * DC);      // 2 MB
  float* CPW  = RP + (size_t)NTOT * 64;                 // 8 MB (per-wave col slots)
  float* pos2 = CPW + (size_t)NTOT * 256;               // 16 KB

  convert_kernel<<<1280, 256, 0, stream>>>(z_i, z_j, c_i, c_j, zbT, cbT, pos2, (float*)d_out);
  fused_kernel<<<8320, 64, 0, stream>>>(zbT, cbT, RP, CPW);
  finalize_kernel<<<512, 1024, 0, stream>>>(RP, CPW, pos2, (float*)d_out);
}